// Round 5
// baseline (246.936 us; speedup 1.0000x reference)
//
#include <hip/hip_runtime.h>

#define DIM 64
#define MAXBUCK 2560
#define SORT_T 1024

// ---- single-block counting sort by m2>>7; emits i1/i2 already gathered
//      into sorted order (removes one indirection level from main) ----
__global__ __launch_bounds__(1024) void k_sort(const int* __restrict__ m1,
                                               const int* __restrict__ m2,
                                               int* __restrict__ i1s,
                                               int* __restrict__ i2s,
                                               int N, int nbuck)
{
    __shared__ int cnt[MAXBUCK];
    __shared__ int s[SORT_T];
    const int tid = threadIdx.x;

    for (int i = tid; i < nbuck; i += SORT_T) cnt[i] = 0;
    __syncthreads();
    for (int i = tid; i < N; i += SORT_T) atomicAdd(&cnt[m2[i] >> 7], 1);
    __syncthreads();

    const int base = tid * 3;
    int loc[3];
    int sum = 0;
    #pragma unroll
    for (int u = 0; u < 3; ++u) {
        const int idx = base + u;
        const int v = (idx < nbuck) ? cnt[idx] : 0;
        loc[u] = sum;
        sum += v;
    }
    s[tid] = sum;
    __syncthreads();
    for (int off = 1; off < SORT_T; off <<= 1) {
        const int v = (tid >= off) ? s[tid - off] : 0;
        __syncthreads();
        s[tid] += v;
        __syncthreads();
    }
    const int excl = (tid > 0) ? s[tid - 1] : 0;
    #pragma unroll
    for (int u = 0; u < 3; ++u) {
        const int idx = base + u;
        if (idx < nbuck) cnt[idx] = excl + loc[u];
    }
    __syncthreads();
    for (int i = tid; i < N; i += SORT_T) {
        const int pos = atomicAdd(&cnt[m2[i] >> 7], 1);
        i1s[pos] = m1[i];
        i2s[pos] = m2[i];
    }
}

// ---- main: one block per sorted match; 32 groups x 8 lanes; one barrier ----
__global__ __launch_bounds__(256) void pixel_ap_main(
    const float* __restrict__ d1, const float* __restrict__ d2,
    const float* __restrict__ qw, const float* __restrict__ qb,
    const int* __restrict__ offs,
    const int* __restrict__ i1s, const int* __restrict__ i2s,
    float* __restrict__ partial, int P, int NEG, int NQ2, int N)
{
    const int tid = threadIdx.x;
    const int nq  = NQ2 >> 1;
    const int M   = NEG + 1;          // 81 scores

    __shared__ float s_scores[96];
    __shared__ float s_red[4];

    // XCD-aware contiguous slice of sorted order (block b -> XCD b%8)
    const int b   = blockIdx.x;
    const int per = gridDim.x >> 3;                 // gridDim = 8*per
    const int pos = (b & 7) * per + (b >> 3);       // bijection onto [0, 8*per)
    if (pos >= N) return;

    const int i1 = i1s[pos];   // uniform -> scalar load path
    const int i2 = i2s[pos];

    const int g  = tid >> 3;          // group 0..31, one score per pass
    const int sl = tid & 7;           // 8 lanes x 32 B = 256 B per row

    // row indices straight from offs[] (L1-hot 320 B): no LDS, no barrier
    int rows[3];
    #pragma unroll
    for (int t = 0; t < 3; ++t) {
        const int j = g + 32 * t;
        if (j < M) rows[t] = (j == 0) ? i2 : min(i2 + offs[j - 1], P - 1);
    }

    const float* a_ptr = d1 + (size_t)i1 * DIM + 8 * sl;
    const float4 a0 = ((const float4*)a_ptr)[0];
    const float4 a1 = ((const float4*)a_ptr)[1];

    float4 b0[3], b1[3];
    #pragma unroll
    for (int t = 0; t < 3; ++t) {
        const int j = g + 32 * t;
        if (j < M) {
            const float* p = d2 + (size_t)rows[t] * DIM + 8 * sl;
            b0[t] = ((const float4*)p)[0];
            b1[t] = ((const float4*)p)[1];
        }
    }
    #pragma unroll
    for (int t = 0; t < 3; ++t) {
        const int j = g + 32 * t;
        if (j < M) {
            float sd = b0[t].x * a0.x + b0[t].y * a0.y + b0[t].z * a0.z + b0[t].w * a0.w
                     + b1[t].x * a1.x + b1[t].y * a1.y + b1[t].z * a1.z + b1[t].w * a1.w;
            sd += __shfl_xor(sd, 1);
            sd += __shfl_xor(sd, 2);
            sd += __shfl_xor(sd, 4);
            if (sl == 0) s_scores[j] = sd;
        }
    }
    __syncthreads();
    if (tid >= 128) return;           // waves 2,3 retire; epilogue on 2 waves

    // ---- hat-basis AP epilogue (exact; validated R2-R4) ----
    const float a_scale = qw[nq];               // +a
    const float amn     = qb[nq - 1] - 1.0f;    // a*mn
    const float ulim    = (float)(nq - 1);

    const float xp = s_scores[0];
    const float up = fminf(fmaxf(a_scale * xp - amn, 0.0f), ulim);
    const float ip = floorf(up);
    const float fp = up - ip;

    float n1 = 0.0f, n2 = 0.0f;
    if (tid < M) {
        const float x  = s_scores[tid];
        const float u  = fminf(fmaxf(a_scale * x - amn, 0.0f), ulim);
        const float fi = floorf(u);
        const float f  = u - fi;
        n2 = (fi >= ip)        ? 1.0f : ((fi == ip - 1.0f) ? f : 0.0f);
        n1 = (fi >= ip + 1.0f) ? 1.0f : ((fi == ip)        ? f : 0.0f);
    }
    #pragma unroll
    for (int off = 32; off >= 1; off >>= 1) {
        n1 += __shfl_xor(n1, off);
        n2 += __shfl_xor(n2, off);
    }
    const int wid = tid >> 6;         // 0 or 1
    if ((tid & 63) == 0) { s_red[wid] = n1; s_red[2 + wid] = n2; }
    __syncthreads();
    if (tid == 0) {
        const float N1 = s_red[0] + s_red[1];
        const float N2 = s_red[2] + s_red[3];
        const float ap = fp * fp / (1e-16f + N1) + (1.0f - fp) / (1e-16f + N2);
        partial[pos] = 1.0f - ap;
    }
}

// ---- single-block final reduction ----
__global__ __launch_bounds__(1024) void k_reduce(const float* __restrict__ partial,
                                                 float* __restrict__ out, int N)
{
    float s = 0.0f;
    for (int i = threadIdx.x; i < N; i += 1024) s += partial[i];
    #pragma unroll
    for (int off = 32; off >= 1; off >>= 1) s += __shfl_xor(s, off);
    __shared__ float sw[16];
    if ((threadIdx.x & 63) == 0) sw[threadIdx.x >> 6] = s;
    __syncthreads();
    if (threadIdx.x == 0) {
        float t = 0.0f;
        #pragma unroll
        for (int w = 0; w < 16; ++w) t += sw[w];
        out[0] = t / (float)N;
    }
}

extern "C" void kernel_launch(void* const* d_in, const int* in_sizes, int n_in,
                              void* d_out, int out_size, void* d_ws, size_t ws_size,
                              hipStream_t stream) {
    const float* d1   = (const float*)d_in[0];
    const float* d2   = (const float*)d_in[1];
    const float* qw   = (const float*)d_in[2];
    const float* qb   = (const float*)d_in[3];
    const int*   m1   = (const int*)d_in[4];
    const int*   m2   = (const int*)d_in[5];
    const int*   offs = (const int*)d_in[6];

    const int N     = in_sizes[4];
    const int P     = in_sizes[0] / DIM;
    const int NEG   = in_sizes[6];
    const int NQ2   = in_sizes[2];
    const int nbuck = (P + 127) >> 7;

    int*   i1s     = (int*)d_ws;
    int*   i2s     = i1s + N;
    float* partial = (float*)(i2s + N);

    k_sort<<<1, SORT_T, 0, stream>>>(m1, m2, i1s, i2s, N, nbuck);

    const int per = (N + 7) / 8;
    pixel_ap_main<<<8 * per, 256, 0, stream>>>(d1, d2, qw, qb, offs, i1s, i2s,
                                               partial, P, NEG, NQ2, N);

    k_reduce<<<1, 1024, 0, stream>>>(partial, (float*)d_out, N);
}

// Round 6
// 202.783 us; speedup vs baseline: 1.2177x; 1.2177x over previous
//
#include <hip/hip_runtime.h>

#define DIM 64

// ---- parallel counting-sort pipeline: zero(memset) -> hist -> scan -> scatter

__global__ __launch_bounds__(256) void k_hist(const int* __restrict__ m2,
                                              int* __restrict__ cnt, int N) {
    const int i = blockIdx.x * 256 + threadIdx.x;
    if (i < N) atomicAdd(&cnt[m2[i] >> 7], 1);
}

// exclusive scan over nbuck (<= 2560) counts, in place, one block of 256
__global__ __launch_bounds__(256) void k_scan(int* __restrict__ cnt, int nbuck) {
    __shared__ int s[256];
    const int tid  = threadIdx.x;
    const int base = tid * 10;
    int loc[10];
    int sum = 0;
    #pragma unroll
    for (int u = 0; u < 10; ++u) {
        const int idx = base + u;
        const int v = (idx < nbuck) ? cnt[idx] : 0;
        loc[u] = sum;
        sum += v;
    }
    s[tid] = sum;
    __syncthreads();
    for (int off = 1; off < 256; off <<= 1) {
        const int v = (tid >= off) ? s[tid - off] : 0;
        __syncthreads();
        s[tid] += v;
        __syncthreads();
    }
    const int excl = (tid > 0) ? s[tid - 1] : 0;
    #pragma unroll
    for (int u = 0; u < 10; ++u) {
        const int idx = base + u;
        if (idx < nbuck) cnt[idx] = excl + loc[u];
    }
}

__global__ __launch_bounds__(256) void k_scatter(const int* __restrict__ m1,
                                                 const int* __restrict__ m2,
                                                 int* __restrict__ cnt,
                                                 int* __restrict__ i1s,
                                                 int* __restrict__ i2s, int N) {
    const int i = blockIdx.x * 256 + threadIdx.x;
    if (i < N) {
        const int v2  = m2[i];
        const int pos = atomicAdd(&cnt[v2 >> 7], 1);
        i1s[pos] = m1[i];
        i2s[pos] = v2;
    }
}

// ---- main: one block per sorted match; 32 groups x 8 lanes; one barrier ----
__global__ __launch_bounds__(256) void pixel_ap_main(
    const float* __restrict__ d1, const float* __restrict__ d2,
    const float* __restrict__ qw, const float* __restrict__ qb,
    const int* __restrict__ offs,
    const int* __restrict__ i1s, const int* __restrict__ i2s,
    float* __restrict__ partial, int P, int NEG, int NQ2, int N)
{
    const int tid = threadIdx.x;
    const int nq  = NQ2 >> 1;
    const int M   = NEG + 1;          // 81 scores

    __shared__ float s_scores[96];
    __shared__ float s_red[4];

    // XCD-aware contiguous slice of sorted order (block b -> XCD b%8)
    const int b   = blockIdx.x;
    const int per = gridDim.x >> 3;                 // gridDim = 8*per
    const int pos = (b & 7) * per + (b >> 3);       // bijection onto [0, 8*per)
    if (pos >= N) return;

    const int i1 = i1s[pos];
    const int i2 = i2s[pos];

    const int g  = tid >> 3;          // group 0..31, one score per pass
    const int sl = tid & 7;           // 8 lanes x 32 B = 256 B per row

    int rows[3];
    #pragma unroll
    for (int t = 0; t < 3; ++t) {
        const int j = g + 32 * t;
        if (j < M) rows[t] = (j == 0) ? i2 : min(i2 + offs[j - 1], P - 1);
    }

    const float* a_ptr = d1 + (size_t)i1 * DIM + 8 * sl;
    const float4 a0 = ((const float4*)a_ptr)[0];
    const float4 a1 = ((const float4*)a_ptr)[1];

    float4 b0[3], b1[3];
    #pragma unroll
    for (int t = 0; t < 3; ++t) {
        const int j = g + 32 * t;
        if (j < M) {
            const float* p = d2 + (size_t)rows[t] * DIM + 8 * sl;
            b0[t] = ((const float4*)p)[0];
            b1[t] = ((const float4*)p)[1];
        }
    }
    #pragma unroll
    for (int t = 0; t < 3; ++t) {
        const int j = g + 32 * t;
        if (j < M) {
            float sd = b0[t].x * a0.x + b0[t].y * a0.y + b0[t].z * a0.z + b0[t].w * a0.w
                     + b1[t].x * a1.x + b1[t].y * a1.y + b1[t].z * a1.z + b1[t].w * a1.w;
            sd += __shfl_xor(sd, 1);
            sd += __shfl_xor(sd, 2);
            sd += __shfl_xor(sd, 4);
            if (sl == 0) s_scores[j] = sd;
        }
    }
    __syncthreads();
    if (tid >= 128) return;           // waves 2,3 retire; epilogue on 2 waves

    // ---- hat-basis AP epilogue (exact; validated R2-R5) ----
    const float a_scale = qw[nq];               // +a
    const float amn     = qb[nq - 1] - 1.0f;    // a*mn
    const float ulim    = (float)(nq - 1);

    const float xp = s_scores[0];
    const float up = fminf(fmaxf(a_scale * xp - amn, 0.0f), ulim);
    const float ip = floorf(up);
    const float fp = up - ip;

    float n1 = 0.0f, n2 = 0.0f;
    if (tid < M) {
        const float x  = s_scores[tid];
        const float u  = fminf(fmaxf(a_scale * x - amn, 0.0f), ulim);
        const float fi = floorf(u);
        const float f  = u - fi;
        n2 = (fi >= ip)        ? 1.0f : ((fi == ip - 1.0f) ? f : 0.0f);
        n1 = (fi >= ip + 1.0f) ? 1.0f : ((fi == ip)        ? f : 0.0f);
    }
    #pragma unroll
    for (int off = 32; off >= 1; off >>= 1) {
        n1 += __shfl_xor(n1, off);
        n2 += __shfl_xor(n2, off);
    }
    const int wid = tid >> 6;         // 0 or 1
    if ((tid & 63) == 0) { s_red[wid] = n1; s_red[2 + wid] = n2; }
    __syncthreads();
    if (tid == 0) {
        const float N1 = s_red[0] + s_red[1];
        const float N2 = s_red[2] + s_red[3];
        const float ap = fp * fp / (1e-16f + N1) + (1.0f - fp) / (1e-16f + N2);
        partial[pos] = 1.0f - ap;
    }
}

// ---- single-block final reduction ----
__global__ __launch_bounds__(1024) void k_reduce(const float* __restrict__ partial,
                                                 float* __restrict__ out, int N)
{
    float s = 0.0f;
    for (int i = threadIdx.x; i < N; i += 1024) s += partial[i];
    #pragma unroll
    for (int off = 32; off >= 1; off >>= 1) s += __shfl_xor(s, off);
    __shared__ float sw[16];
    if ((threadIdx.x & 63) == 0) sw[threadIdx.x >> 6] = s;
    __syncthreads();
    if (threadIdx.x == 0) {
        float t = 0.0f;
        #pragma unroll
        for (int w = 0; w < 16; ++w) t += sw[w];
        out[0] = t / (float)N;
    }
}

extern "C" void kernel_launch(void* const* d_in, const int* in_sizes, int n_in,
                              void* d_out, int out_size, void* d_ws, size_t ws_size,
                              hipStream_t stream) {
    const float* d1   = (const float*)d_in[0];
    const float* d2   = (const float*)d_in[1];
    const float* qw   = (const float*)d_in[2];
    const float* qb   = (const float*)d_in[3];
    const int*   m1   = (const int*)d_in[4];
    const int*   m2   = (const int*)d_in[5];
    const int*   offs = (const int*)d_in[6];

    const int N     = in_sizes[4];
    const int P     = in_sizes[0] / DIM;
    const int NEG   = in_sizes[6];
    const int NQ2   = in_sizes[2];
    const int nbuck = (P + 127) >> 7;

    int*   cnt     = (int*)d_ws;
    int*   i1s     = cnt + nbuck;
    int*   i2s     = i1s + N;
    float* partial = (float*)(i2s + N);

    const int nblk = (N + 255) / 256;

    hipMemsetAsync(cnt, 0, (size_t)nbuck * sizeof(int), stream);
    k_hist   <<<nblk, 256, 0, stream>>>(m2, cnt, N);
    k_scan   <<<1, 256, 0, stream>>>(cnt, nbuck);
    k_scatter<<<nblk, 256, 0, stream>>>(m1, m2, cnt, i1s, i2s, N);

    const int per = (N + 7) / 8;
    pixel_ap_main<<<8 * per, 256, 0, stream>>>(d1, d2, qw, qb, offs, i1s, i2s,
                                               partial, P, NEG, NQ2, N);

    k_reduce<<<1, 1024, 0, stream>>>(partial, (float*)d_out, N);
}